// Round 18
// baseline (56.731 us; speedup 1.0000x reference)
//
#include <hip/hip_runtime.h>

#define CLIP 4096
#define H1   2048
#define H2   1024
#define RN   4096
#define H_STEP 2.44140625f   // r_i = H_STEP*(i+1) exactly
#define G1   32768           // Sturm grid points per l

// ---- monotone float<->uint map for atomic min/max of floats -----------------
__device__ __forceinline__ unsigned fmap(float f) {
    unsigned u = __float_as_uint(f);
    return (u & 0x80000000u) ? ~u : (u | 0x80000000u);
}
__device__ __forceinline__ float funmap(unsigned u) {
    return __uint_as_float((u & 0x80000000u) ? (u & 0x7fffffffu) : ~u);
}
__device__ __forceinline__ void spect_bounds(const unsigned* bu, float& lo, float& cell) {
    float mn = funmap(bu[0]), mx = funmap(bu[1]);
    lo = mn - 1e-3f;                              // Gershgorin: lambda_min >= min ptl
    float hi = mx + 2.33554432f + 1e-3f;          // lambda_max <= max ptl + 2 + 2/r0^2
    cell = (hi - lo) * (1.0f / (float)G1);
}

// ---------------- Layer 1 split-K partials: partA[c][j] ----------------------
__global__ __launch_bounds__(256) void part1(const float* __restrict__ W,
                                             const float* __restrict__ x,
                                             float* __restrict__ partA,
                                             unsigned* __restrict__ bu) {
    if (blockIdx.x == 0 && blockIdx.y == 0 && threadIdx.x == 0) {
        bu[0] = 0xFFFFFFFFu;   // running min (mapped)
        bu[1] = 0u;            // running max (mapped)
    }
    int j = blockIdx.x * 256 + threadIdx.x;       // 8 x-blocks -> j < 2048
    int i0 = blockIdx.y * 64;                     // 64 k-chunks of 64 rows
    const float* Wp = W + (size_t)i0 * H1 + j;
    float acc = 0.f;
#pragma unroll 8
    for (int i = 0; i < 64; ++i)
        acc = fmaf(x[i0 + i], Wp[(size_t)i * H1], acc);   // x uniform -> s_load
    partA[(size_t)blockIdx.y * H1 + j] = acc;
}

// ------- Layer 2, fused: prologue reduces the 16 h1 values this block needs --
__global__ __launch_bounds__(256) void part2f(const float* __restrict__ W,
                                              const float* __restrict__ partA,
                                              const float* __restrict__ b,
                                              float* __restrict__ partB) {
    __shared__ float xs[16];
    int t = threadIdx.x;
    int i_loc = t >> 4, c_loc = t & 15;           // 16 i's x 16 lanes
    int i0 = blockIdx.y * 16;                     // 128 k-chunks of 16 rows
    float s = 0.f;
#pragma unroll
    for (int k = 0; k < 4; ++k)                   // 64 layer-1 partials
        s += partA[(size_t)(c_loc + 16 * k) * H1 + i0 + i_loc];
    s += __shfl_xor(s, 1); s += __shfl_xor(s, 2);
    s += __shfl_xor(s, 4); s += __shfl_xor(s, 8);
    if (c_loc == 0) xs[i_loc] = fmaxf(s + b[i0 + i_loc], 0.f);
    __syncthreads();
    float xv[16];
#pragma unroll
    for (int u = 0; u < 16; ++u) xv[u] = xs[u];
    int j = blockIdx.x * 256 + t;                 // 4 x-blocks -> j < 1024
    const float* Wp = W + (size_t)i0 * H2 + j;
    float acc = 0.f;
#pragma unroll
    for (int i = 0; i < 16; ++i)
        acc = fmaf(xv[i], Wp[(size_t)i * H2], acc);
    partB[(size_t)blockIdx.y * H2 + j] = acc;
}

// ------- Layer 3, fused: prologue reduces the 32 h2 values this block needs --
__global__ __launch_bounds__(256) void part3f(const float* __restrict__ W,
                                              const float* __restrict__ partB,
                                              const float* __restrict__ b,
                                              float* __restrict__ partA) {
    __shared__ float xs[32];
    int t = threadIdx.x;
    int i_loc = t >> 3, c_loc = t & 7;            // 32 i's x 8 lanes
    int i0 = blockIdx.y * 32;                     // 32 k-chunks of 32 rows
    float s = 0.f;
#pragma unroll
    for (int k = 0; k < 16; ++k)                  // 128 layer-2 partials
        s += partB[(size_t)(c_loc + 8 * k) * H2 + i0 + i_loc];
    s += __shfl_xor(s, 1); s += __shfl_xor(s, 2); s += __shfl_xor(s, 4);
    if (c_loc == 0) xs[i_loc] = fmaxf(s + b[i0 + i_loc], 0.f);
    __syncthreads();
    float xv[32];
#pragma unroll
    for (int u = 0; u < 32; ++u) xv[u] = xs[u];
    int j = blockIdx.x * 256 + t;                 // 16 x-blocks -> j < 4096
    const float* Wp = W + (size_t)i0 * RN + j;
    float acc = 0.f;
#pragma unroll
    for (int i = 0; i < 32; ++i)
        acc = fmaf(xv[i], Wp[(size_t)i * RN], acc);
    partA[(size_t)blockIdx.y * RN + j] = acc;
}

// ---- Final fin: ptl -> d_out, D0/D1 = 2*diag (contiguous), spectral bounds --
__global__ __launch_bounds__(256) void fin3(const float* __restrict__ partA,
                                            const float* __restrict__ b,
                                            float* __restrict__ out,
                                            float* __restrict__ D,
                                            unsigned* __restrict__ bu) {
    __shared__ float smn[4], smx[4];
    int j = blockIdx.x * 256 + threadIdx.x;
    float s = b[j];
#pragma unroll 8
    for (int c = 0; c < 32; ++c) s += partA[(size_t)c * RN + j];
    out[j] = s;                                   // ptl -> d_out[0:RN]
    float r = H_STEP * (float)(j + 1);
    float base = 2.0f + 2.0f * s;                 // 2*(1 + ptl)
    D[j] = base;                                  // l = 0
    D[RN + j] = base + 4.0f / (r * r);            // l = 1: + 2*l(l+1)/r^2
    float mn = s, mx = s;
    for (int off = 32; off; off >>= 1) {
        mn = fminf(mn, __shfl_down(mn, off));
        mx = fmaxf(mx, __shfl_down(mx, off));
    }
    int tid = threadIdx.x;
    if ((tid & 63) == 0) { smn[tid >> 6] = mn; smx[tid >> 6] = mx; }
    __syncthreads();
    if (tid == 0) {
        for (int w = 1; w < 4; ++w) { mn = fminf(mn, smn[w]); mx = fmaxf(mx, smx[w]); }
        atomicMin(&bu[0], fmap(mn));
        atomicMax(&bu[1], fmap(mx));
    }
}

// -------- Sturm count via sign-alternating transform (verified R11) ----------
// u'_k = t'_k u'_{k-1} + u'_{k-2}, t' alternating (D-X)/(X-D); mask 0x5555.
#define STEP_B(dv)                                                         \
    {                                                                      \
        float tt = (dv) - X;                                               \
        float p = fmaf(tt, pm1, pm2);                                      \
        r = __builtin_amdgcn_alignbit(r, __float_as_uint(p), 31);          \
        pm2 = pm1; pm1 = p;                                                \
    }
#define STEP_A(dv)                                                         \
    {                                                                      \
        float tt = X - (dv);                                               \
        float p = fmaf(tt, pm1, pm2);                                      \
        r = __builtin_amdgcn_alignbit(r, __float_as_uint(p), 31);          \
        pm2 = pm1; pm1 = p;                                                \
    }
#define CNT16                                                              \
    {                                                                      \
        unsigned xx = ((r ^ (r >> 1)) ^ 0x5555u) & 0xFFFFu;                \
        cnt += (unsigned)__builtin_popcount(xx);                           \
    }
#define RENORM                                                             \
    {                                                                      \
        unsigned a1 = __float_as_uint(pm1) & 0x7fffffffu;                  \
        unsigned a2 = __float_as_uint(pm2) & 0x7fffffffu;                  \
        unsigned hm = a1 > a2 ? a1 : a2;                                   \
        int es = 254 - (int)(hm >> 23);                                    \
        es = es < 1 ? 1 : es;                                              \
        float sc = __uint_as_float((unsigned)es << 23);                    \
        pm1 *= sc; pm2 *= sc;                                              \
    }
#define GRP16(v0, v1, v2, v3)                                              \
    {                                                                      \
        STEP_B(v0.x) STEP_A(v0.y) STEP_B(v0.z) STEP_A(v0.w)                \
        STEP_B(v1.x) STEP_A(v1.y) STEP_B(v1.z) STEP_A(v1.w)                \
        STEP_B(v2.x) STEP_A(v2.y) STEP_B(v2.z) STEP_A(v2.w)                \
        STEP_B(v3.x) STEP_A(v3.y) STEP_B(v3.z) STEP_A(v3.w)                \
        CNT16                                                              \
        RENORM                                                             \
    }
// load one 16-float4 half-OCT into a register array (static indices)
#define LOADH(BUF, base)                                                   \
    {                                                                      \
        _Pragma("unroll")                                                  \
        for (int q = 0; q < 16; ++q) BUF[q] = (base)[q];                   \
    }
// compute 64 steps from a register array
#define COMPH(BUF)                                                         \
    {                                                                      \
        _Pragma("unroll")                                                  \
        for (int q = 0; q < 4; ++q)                                        \
            GRP16(BUF[4 * q], BUF[4 * q + 1], BUF[4 * q + 2], BUF[4 * q + 3]) \
    }

// Twisted-factorization bidirectional Sturm with explicit register
// double-buffering: load next 64-step half-OCT into B, sched_barrier(0) pins
// the loads issued, then compute A (~470 cyc) while B's LDS reads land.
// Waves 0-1: fwd over ds[0..2047]; waves 2-3: bwd over dsrev[0..2046].
// count = SCfwd + SCbwd + [gamma_m < 0] at twist m=2048. 2048 waves = 2/SIMD.
__global__ __launch_bounds__(256) void stage1(const float* __restrict__ Dall,
                                              const unsigned* __restrict__ bu,
                                              int* __restrict__ counts) {
    __shared__ alignas(16) float ds[RN];
    __shared__ alignas(16) float dsrev[RN];
    __shared__ float shB1[128], shB2[128];
    __shared__ int   shCB[128];
    const int t = threadIdx.x, l = blockIdx.y;
    const float* Dsrc = Dall + (l << 12);
    for (int i = t; i < RN / 4; i += 256) {
        float4 v = reinterpret_cast<const float4*>(Dsrc)[i];
        reinterpret_cast<float4*>(ds)[i] = v;
        reinterpret_cast<float4*>(dsrev)[RN / 4 - 1 - i] =
            make_float4(v.w, v.z, v.y, v.x);
    }
    __syncthreads();

    float lo, cell;
    spect_bounds(bu, lo, cell);
    int xi = t & 127, dir = t >> 7;               // dir wave-uniform (128 = 2 waves)
    int j = blockIdx.x * 128 + xi;                // 256 x-blocks -> j < 32768
    float X = 2.0f * (lo + cell * (float)j);

    float pm1 = 1.0f, pm2 = 0.0f;                 // u'_0 = 1, u'_{-1} = 0
    unsigned cnt = 0, r = 0;
    const float4* d4 = reinterpret_cast<const float4*>(dir == 0 ? ds : dsrev);
    float4 A[16], B[16];

    if (dir == 0) {
        // forward: 32 half-OCTs (h*16 float4), 2048 steps
        LOADH(A, d4)
        for (int w = 0; w < 16; ++w) {
            const float4* gB = d4 + (((w * 2 + 1) & 31) << 4);
            LOADH(B, gB)
            __builtin_amdgcn_sched_barrier(0);
            COMPH(A)
            const float4* gA = d4 + (((w * 2 + 2) & 31) << 4);   // wraps at end
            LOADH(A, gA)
            __builtin_amdgcn_sched_barrier(0);
            COMPH(B)
        }
        // -> pm1 = u'_2048, pm2 = u'_2047
    } else {
        // backward over dsrev: halves 0..30 (1984 steps) + half 31 partial (63)
        LOADH(A, d4)
        for (int w = 0; w < 15; ++w) {            // halves 0..29
            const float4* gB = d4 + (((w * 2 + 1) & 31) << 4);
            LOADH(B, gB)
            __builtin_amdgcn_sched_barrier(0);
            COMPH(A)
            const float4* gA = d4 + (((w * 2 + 2) & 31) << 4);
            LOADH(A, gA)
            __builtin_amdgcn_sched_barrier(0);
            COMPH(B)
        }
        // A now holds half 30 (loaded at w=14 tail)
        LOADH(B, d4 + 496)                        // half 31: dsrev[1984..2046]
        __builtin_amdgcn_sched_barrier(0);
        COMPH(A)                                  // steps -> 1984 total
        GRP16(B[0], B[1], B[2], B[3])             // +16 -> 2000
        GRP16(B[4], B[5], B[6], B[7])             // +16 -> 2016
        GRP16(B[8], B[9], B[10], B[11])           // +16 -> 2032
        {   // tail 15 steps: dsrev[2032..2046]; parity mask 0x2AAA
            STEP_B(B[12].x) STEP_A(B[12].y) STEP_B(B[12].z) STEP_A(B[12].w)
            STEP_B(B[13].x) STEP_A(B[13].y) STEP_B(B[13].z) STEP_A(B[13].w)
            STEP_B(B[14].x) STEP_A(B[14].y) STEP_B(B[14].z) STEP_A(B[14].w)
            STEP_B(B[15].x) STEP_A(B[15].y) STEP_B(B[15].z)
            unsigned xx = ((r ^ (r >> 1)) ^ 0x2AAAu) & 0x7FFFu;
            cnt += (unsigned)__builtin_popcount(xx);
        }
        shB1[xi] = pm1; shB2[xi] = pm2; shCB[xi] = (int)cnt;
    }
    __syncthreads();
    if (dir == 0) {
        // twist combine at m=2048: gammaN = -(Dm-X)u'1w'1 - u'2w'1 + u'1w'2;
        // [gamma<0] = !(sg^su^sw)
        float u1 = pm1, u2 = pm2;
        float w1 = shB1[xi], w2 = shB2[xi];
        float Dm = ds[2048];
        float gg = -(Dm - X) * u1 * w1 - u2 * w1 + u1 * w2;
        unsigned sx = (__float_as_uint(gg) ^ __float_as_uint(u1) ^
                       __float_as_uint(w1)) >> 31;
        counts[(l << 15) + j] = (int)(cnt + (unsigned)shCB[xi] + (sx ^ 1u));
    }
}

// ------------- final: bracket search (noise-tolerant) + midpoint -------------
__global__ __launch_bounds__(256) void final_eig(const int* __restrict__ counts,
                                                 const unsigned* __restrict__ bu,
                                                 float* __restrict__ out) {
    int e = blockIdx.x * 256 + threadIdx.x;       // 8192 eigenvalues (l,k)
    int l = e >> 12, k = e & (RN - 1);
    const int* c = counts + (l << 15);
    int lo_i = 0, hi_i = G1 - 1;                  // last j with c[j] <= k
    while (lo_i < hi_i) {
        int mid = (lo_i + hi_i + 1) >> 1;
        if (c[mid] <= k) lo_i = mid; else hi_i = mid - 1;
    }
    while (lo_i > 0 && c[lo_i] > k) --lo_i;       // +-1 noise fixups
    while (lo_i < G1 - 1 && c[lo_i + 1] <= k) ++lo_i;
    float lo, cell;
    spect_bounds(bu, lo, cell);
    out[e] = lo + cell * ((float)lo_i + 0.5f);
}

extern "C" void kernel_launch(void* const* d_in, const int* in_sizes, int n_in,
                              void* d_out, int out_size, void* d_ws, size_t ws_size,
                              hipStream_t stream) {
    const float* energy = (const float*)d_in[0];
    const float* W1 = (const float*)d_in[1];
    const float* b1 = (const float*)d_in[2];
    const float* W2 = (const float*)d_in[3];
    const float* b2 = (const float*)d_in[4];
    const float* W3 = (const float*)d_in[5];
    const float* b3 = (const float*)d_in[6];
    float* out = (float*)d_out;                   // [RN] ptl, then [2*RN] eigenvalues

    float* ws = (float*)d_ws;
    float*    partA  = ws;                        // 131072 f32 (layers 1,3)
    float*    partB  = partA + 131072;            // 131072 f32 (layer 2)
    float*    D      = partB + 131072;            // 2*RN f32 (D0 | D1)
    unsigned* bu     = (unsigned*)(D + 2 * RN);   // 2 u32
    int*      counts = (int*)(bu + 4);            // 2*G1 i32 (256 KB)

    // ---- MLP: 3 GEMVs, fins fused into next layer's prologue (R14 config) ----
    part1 <<<dim3(8, 64),  256, 0, stream>>>(W1, energy, partA, bu);
    part2f<<<dim3(4, 128), 256, 0, stream>>>(W2, partA, b1, partB);
    part3f<<<dim3(16, 32), 256, 0, stream>>>(W3, partB, b2, partA);
    fin3  <<<RN / 256,     256, 0, stream>>>(partA, b3, out, D, bu);

    // ---- Eigenvalues: twisted Sturm, reg double-buffer + sched_barrier ----
    stage1<<<dim3(G1 / 128, 2), 256, 0, stream>>>(D, bu, counts);
    final_eig<<<2 * RN / 256, 256, 0, stream>>>(counts, bu, out + RN);
}

// Round 19
// 55.483 us; speedup vs baseline: 1.0225x; 1.0225x over previous
//
#include <hip/hip_runtime.h>

#define CLIP 4096
#define H1   2048
#define H2   1024
#define RN   4096
#define H_STEP 2.44140625f   // r_i = H_STEP*(i+1) exactly
#define G1   32768           // Sturm grid points per l

// ---- monotone float<->uint map for atomic min/max of floats -----------------
__device__ __forceinline__ unsigned fmap(float f) {
    unsigned u = __float_as_uint(f);
    return (u & 0x80000000u) ? ~u : (u | 0x80000000u);
}
__device__ __forceinline__ float funmap(unsigned u) {
    return __uint_as_float((u & 0x80000000u) ? (u & 0x7fffffffu) : ~u);
}
__device__ __forceinline__ void spect_bounds(const unsigned* bu, float& lo, float& cell) {
    float mn = funmap(bu[0]), mx = funmap(bu[1]);
    lo = mn - 1e-3f;                              // Gershgorin: lambda_min >= min ptl
    float hi = mx + 2.33554432f + 1e-3f;          // lambda_max <= max ptl + 2 + 2/r0^2
    cell = (hi - lo) * (1.0f / (float)G1);
}

// ---------------- Layer 1 split-K partials: partA[c][j] ----------------------
__global__ __launch_bounds__(256) void part1(const float* __restrict__ W,
                                             const float* __restrict__ x,
                                             float* __restrict__ partA,
                                             unsigned* __restrict__ bu) {
    if (blockIdx.x == 0 && blockIdx.y == 0 && threadIdx.x == 0) {
        bu[0] = 0xFFFFFFFFu;   // running min (mapped)
        bu[1] = 0u;            // running max (mapped)
    }
    int j = blockIdx.x * 256 + threadIdx.x;       // 8 x-blocks -> j < 2048
    int i0 = blockIdx.y * 64;                     // 64 k-chunks of 64 rows
    const float* Wp = W + (size_t)i0 * H1 + j;
    float acc = 0.f;
#pragma unroll 8
    for (int i = 0; i < 64; ++i)
        acc = fmaf(x[i0 + i], Wp[(size_t)i * H1], acc);   // x uniform -> s_load
    partA[(size_t)blockIdx.y * H1 + j] = acc;
}

// ------- Layer 2, fused: prologue reduces the 16 h1 values this block needs --
__global__ __launch_bounds__(256) void part2f(const float* __restrict__ W,
                                              const float* __restrict__ partA,
                                              const float* __restrict__ b,
                                              float* __restrict__ partB) {
    __shared__ float xs[16];
    int t = threadIdx.x;
    int i_loc = t >> 4, c_loc = t & 15;           // 16 i's x 16 lanes
    int i0 = blockIdx.y * 16;                     // 128 k-chunks of 16 rows
    float s = 0.f;
#pragma unroll
    for (int k = 0; k < 4; ++k)                   // 64 layer-1 partials
        s += partA[(size_t)(c_loc + 16 * k) * H1 + i0 + i_loc];
    s += __shfl_xor(s, 1); s += __shfl_xor(s, 2);
    s += __shfl_xor(s, 4); s += __shfl_xor(s, 8);
    if (c_loc == 0) xs[i_loc] = fmaxf(s + b[i0 + i_loc], 0.f);
    __syncthreads();
    float xv[16];
#pragma unroll
    for (int u = 0; u < 16; ++u) xv[u] = xs[u];
    int j = blockIdx.x * 256 + t;                 // 4 x-blocks -> j < 1024
    const float* Wp = W + (size_t)i0 * H2 + j;
    float acc = 0.f;
#pragma unroll
    for (int i = 0; i < 16; ++i)
        acc = fmaf(xv[i], Wp[(size_t)i * H2], acc);
    partB[(size_t)blockIdx.y * H2 + j] = acc;
}

// ------- Layer 3, fused: prologue reduces the 32 h2 values this block needs --
__global__ __launch_bounds__(256) void part3f(const float* __restrict__ W,
                                              const float* __restrict__ partB,
                                              const float* __restrict__ b,
                                              float* __restrict__ partA) {
    __shared__ float xs[32];
    int t = threadIdx.x;
    int i_loc = t >> 3, c_loc = t & 7;            // 32 i's x 8 lanes
    int i0 = blockIdx.y * 32;                     // 32 k-chunks of 32 rows
    float s = 0.f;
#pragma unroll
    for (int k = 0; k < 16; ++k)                  // 128 layer-2 partials
        s += partB[(size_t)(c_loc + 8 * k) * H2 + i0 + i_loc];
    s += __shfl_xor(s, 1); s += __shfl_xor(s, 2); s += __shfl_xor(s, 4);
    if (c_loc == 0) xs[i_loc] = fmaxf(s + b[i0 + i_loc], 0.f);
    __syncthreads();
    float xv[32];
#pragma unroll
    for (int u = 0; u < 32; ++u) xv[u] = xs[u];
    int j = blockIdx.x * 256 + t;                 // 16 x-blocks -> j < 4096
    const float* Wp = W + (size_t)i0 * RN + j;
    float acc = 0.f;
#pragma unroll
    for (int i = 0; i < 32; ++i)
        acc = fmaf(xv[i], Wp[(size_t)i * RN], acc);
    partA[(size_t)blockIdx.y * RN + j] = acc;
}

// ---- Final fin: ptl -> d_out, D0/D1 = 2*diag (contiguous), spectral bounds --
__global__ __launch_bounds__(256) void fin3(const float* __restrict__ partA,
                                            const float* __restrict__ b,
                                            float* __restrict__ out,
                                            float* __restrict__ D,
                                            unsigned* __restrict__ bu) {
    __shared__ float smn[4], smx[4];
    int j = blockIdx.x * 256 + threadIdx.x;
    float s = b[j];
#pragma unroll 8
    for (int c = 0; c < 32; ++c) s += partA[(size_t)c * RN + j];
    out[j] = s;                                   // ptl -> d_out[0:RN]
    float r = H_STEP * (float)(j + 1);
    float base = 2.0f + 2.0f * s;                 // 2*(1 + ptl)
    D[j] = base;                                  // l = 0
    D[RN + j] = base + 4.0f / (r * r);            // l = 1: + 2*l(l+1)/r^2
    float mn = s, mx = s;
    for (int off = 32; off; off >>= 1) {
        mn = fminf(mn, __shfl_down(mn, off));
        mx = fmaxf(mx, __shfl_down(mx, off));
    }
    int tid = threadIdx.x;
    if ((tid & 63) == 0) { smn[tid >> 6] = mn; smx[tid >> 6] = mx; }
    __syncthreads();
    if (tid == 0) {
        for (int w = 1; w < 4; ++w) { mn = fminf(mn, smn[w]); mx = fmaxf(mx, smx[w]); }
        atomicMin(&bu[0], fmap(mn));
        atomicMax(&bu[1], fmap(mx));
    }
}

// -------- Sturm count via sign-alternating transform (verified R11) ----------
// u'_k = t'_k u'_{k-1} + u'_{k-2}, t' alternating (D-X)/(X-D); mask 0x5555.
// C-macro steps (used only for the 15-step bwd tail):
#define STEP_B(dv)                                                         \
    {                                                                      \
        float tt = (dv) - X;                                               \
        float p = fmaf(tt, pm1, pm2);                                      \
        r = __builtin_amdgcn_alignbit(r, __float_as_uint(p), 31);          \
        pm2 = pm1; pm1 = p;                                                \
    }
#define STEP_A(dv)                                                         \
    {                                                                      \
        float tt = X - (dv);                                               \
        float p = fmaf(tt, pm1, pm2);                                      \
        r = __builtin_amdgcn_alignbit(r, __float_as_uint(p), 31);          \
        pm2 = pm1; pm1 = p;                                                \
    }
#define CNT16                                                              \
    {                                                                      \
        unsigned xx = ((r ^ (r >> 1)) ^ 0x5555u) & 0xFFFFu;                \
        cnt += (unsigned)__builtin_popcount(xx);                           \
    }
#define RENORM                                                             \
    {                                                                      \
        unsigned a1 = __float_as_uint(pm1) & 0x7fffffffu;                  \
        unsigned a2 = __float_as_uint(pm2) & 0x7fffffffu;                  \
        unsigned hm = a1 > a2 ? a1 : a2;                                   \
        int es = 254 - (int)(hm >> 23);                                    \
        es = es < 1 ? 1 : es;                                              \
        float sc = __uint_as_float((unsigned)es << 23);                    \
        pm1 *= sc; pm2 *= sc;                                              \
    }

// 16-step group in inline asm: exactly 3 VALU/step, ZERO moves.
// v_fmac_f32 pm2, t, pm1 computes p = t*pm1 + pm2 into the dying pm2 register;
// roles ping-pong each step and return to canonical after 16 (even) steps.
#define GRP16_ASM(v0, v1, v2, v3)                                          \
    {                                                                      \
        float t_;                                                          \
        asm volatile(                                                      \
            "v_sub_f32 %[t], %[dA0], %[X]\n\t"                             \
            "v_fmac_f32 %[p2], %[t], %[p1]\n\t"                            \
            "v_alignbit_b32 %[r], %[r], %[p2], 31\n\t"                     \
            "v_sub_f32 %[t], %[X], %[dA1]\n\t"                             \
            "v_fmac_f32 %[p1], %[t], %[p2]\n\t"                            \
            "v_alignbit_b32 %[r], %[r], %[p1], 31\n\t"                     \
            "v_sub_f32 %[t], %[dA2], %[X]\n\t"                             \
            "v_fmac_f32 %[p2], %[t], %[p1]\n\t"                            \
            "v_alignbit_b32 %[r], %[r], %[p2], 31\n\t"                     \
            "v_sub_f32 %[t], %[X], %[dA3]\n\t"                             \
            "v_fmac_f32 %[p1], %[t], %[p2]\n\t"                            \
            "v_alignbit_b32 %[r], %[r], %[p1], 31\n\t"                     \
            "v_sub_f32 %[t], %[dB0], %[X]\n\t"                             \
            "v_fmac_f32 %[p2], %[t], %[p1]\n\t"                            \
            "v_alignbit_b32 %[r], %[r], %[p2], 31\n\t"                     \
            "v_sub_f32 %[t], %[X], %[dB1]\n\t"                             \
            "v_fmac_f32 %[p1], %[t], %[p2]\n\t"                            \
            "v_alignbit_b32 %[r], %[r], %[p1], 31\n\t"                     \
            "v_sub_f32 %[t], %[dB2], %[X]\n\t"                             \
            "v_fmac_f32 %[p2], %[t], %[p1]\n\t"                            \
            "v_alignbit_b32 %[r], %[r], %[p2], 31\n\t"                     \
            "v_sub_f32 %[t], %[X], %[dB3]\n\t"                             \
            "v_fmac_f32 %[p1], %[t], %[p2]\n\t"                            \
            "v_alignbit_b32 %[r], %[r], %[p1], 31\n\t"                     \
            "v_sub_f32 %[t], %[dC0], %[X]\n\t"                             \
            "v_fmac_f32 %[p2], %[t], %[p1]\n\t"                            \
            "v_alignbit_b32 %[r], %[r], %[p2], 31\n\t"                     \
            "v_sub_f32 %[t], %[X], %[dC1]\n\t"                             \
            "v_fmac_f32 %[p1], %[t], %[p2]\n\t"                            \
            "v_alignbit_b32 %[r], %[r], %[p1], 31\n\t"                     \
            "v_sub_f32 %[t], %[dC2], %[X]\n\t"                             \
            "v_fmac_f32 %[p2], %[t], %[p1]\n\t"                            \
            "v_alignbit_b32 %[r], %[r], %[p2], 31\n\t"                     \
            "v_sub_f32 %[t], %[X], %[dC3]\n\t"                             \
            "v_fmac_f32 %[p1], %[t], %[p2]\n\t"                            \
            "v_alignbit_b32 %[r], %[r], %[p1], 31\n\t"                     \
            "v_sub_f32 %[t], %[dD0], %[X]\n\t"                             \
            "v_fmac_f32 %[p2], %[t], %[p1]\n\t"                            \
            "v_alignbit_b32 %[r], %[r], %[p2], 31\n\t"                     \
            "v_sub_f32 %[t], %[X], %[dD1]\n\t"                             \
            "v_fmac_f32 %[p1], %[t], %[p2]\n\t"                            \
            "v_alignbit_b32 %[r], %[r], %[p1], 31\n\t"                     \
            "v_sub_f32 %[t], %[dD2], %[X]\n\t"                             \
            "v_fmac_f32 %[p2], %[t], %[p1]\n\t"                            \
            "v_alignbit_b32 %[r], %[r], %[p2], 31\n\t"                     \
            "v_sub_f32 %[t], %[X], %[dD3]\n\t"                             \
            "v_fmac_f32 %[p1], %[t], %[p2]\n\t"                            \
            "v_alignbit_b32 %[r], %[r], %[p1], 31\n\t"                     \
            : [p1] "+v"(pm1), [p2] "+v"(pm2), [r] "+v"(r), [t] "=&v"(t_)   \
            : [X] "v"(X),                                                  \
              [dA0] "v"(v0.x), [dA1] "v"(v0.y), [dA2] "v"(v0.z), [dA3] "v"(v0.w), \
              [dB0] "v"(v1.x), [dB1] "v"(v1.y), [dB2] "v"(v1.z), [dB3] "v"(v1.w), \
              [dC0] "v"(v2.x), [dC1] "v"(v2.y), [dC2] "v"(v2.z), [dC3] "v"(v2.w), \
              [dD0] "v"(v3.x), [dD1] "v"(v3.y), [dD2] "v"(v3.z), [dD3] "v"(v3.w)); \
        CNT16                                                              \
        RENORM                                                             \
    }
// 8 consecutive 16-step asm groups with compile-time offsets off one base
#define OCT_ASM(g)                                                         \
    {                                                                      \
        float4 a0 = (g)[0],  a1 = (g)[1],  a2 = (g)[2],  a3 = (g)[3];      \
        GRP16_ASM(a0, a1, a2, a3)                                          \
        float4 b0 = (g)[4],  b1 = (g)[5],  b2 = (g)[6],  b3 = (g)[7];      \
        GRP16_ASM(b0, b1, b2, b3)                                          \
        float4 c0 = (g)[8],  c1 = (g)[9],  c2 = (g)[10], c3 = (g)[11];     \
        GRP16_ASM(c0, c1, c2, c3)                                          \
        float4 e0 = (g)[12], e1 = (g)[13], e2 = (g)[14], e3 = (g)[15];     \
        GRP16_ASM(e0, e1, e2, e3)                                          \
        float4 f0 = (g)[16], f1 = (g)[17], f2 = (g)[18], f3 = (g)[19];     \
        GRP16_ASM(f0, f1, f2, f3)                                          \
        float4 h0 = (g)[20], h1 = (g)[21], h2 = (g)[22], h3 = (g)[23];     \
        GRP16_ASM(h0, h1, h2, h3)                                          \
        float4 i0 = (g)[24], i1 = (g)[25], i2 = (g)[26], i3 = (g)[27];     \
        GRP16_ASM(i0, i1, i2, i3)                                          \
        float4 k0 = (g)[28], k1 = (g)[29], k2 = (g)[30], k3 = (g)[31];     \
        GRP16_ASM(k0, k1, k2, k3)                                          \
    }

// Twisted-factorization bidirectional Sturm: per block, 128 X-values x 2 dirs.
// Waves 0-1: forward u-chain over ds[0..2047]; waves 2-3: backward w-chain
// over dsrev[0..2046] (dsrev[k] = D[4095-k]); both ascending static-offset.
// count = SCfwd + SCbwd + [gamma_m < 0] at twist m=2048. 2048 waves = 2/SIMD.
__global__ __launch_bounds__(256) void stage1(const float* __restrict__ Dall,
                                              const unsigned* __restrict__ bu,
                                              int* __restrict__ counts) {
    __shared__ alignas(16) float ds[RN];
    __shared__ alignas(16) float dsrev[RN];
    __shared__ float shB1[128], shB2[128];
    __shared__ int   shCB[128];
    const int t = threadIdx.x, l = blockIdx.y;
    const float* Dsrc = Dall + (l << 12);
    for (int i = t; i < RN / 4; i += 256) {
        float4 v = reinterpret_cast<const float4*>(Dsrc)[i];
        reinterpret_cast<float4*>(ds)[i] = v;
        reinterpret_cast<float4*>(dsrev)[RN / 4 - 1 - i] =
            make_float4(v.w, v.z, v.y, v.x);
    }
    __syncthreads();

    float lo, cell;
    spect_bounds(bu, lo, cell);
    int xi = t & 127, dir = t >> 7;               // dir wave-uniform (128 = 2 waves)
    int j = blockIdx.x * 128 + xi;                // 256 x-blocks -> j < 32768
    float X = 2.0f * (lo + cell * (float)j);

    float pm1 = 1.0f, pm2 = 0.0f;                 // u'_0 = 1, u'_{-1} = 0
    unsigned cnt = 0, r = 0;
    const float4* d4 = reinterpret_cast<const float4*>(dir == 0 ? ds : dsrev);

    if (dir == 0) {
        // forward: 16 x OCT = 2048 steps -> pm1 = u'_2048, pm2 = u'_2047
        for (int w = 0; w < 16; ++w) {
            const float4* g = d4 + w * 32;
            OCT_ASM(g)
        }
    } else {
        // backward: 15 x OCT + 7 groups + 15-step tail = 2047 steps over dsrev
        for (int w = 0; w < 15; ++w) {
            const float4* g = d4 + w * 32;
            OCT_ASM(g)
        }
        {
            const float4* g = d4 + 480;           // 7 groups: dsrev[1920..2031]
#pragma unroll
            for (int q = 0; q < 7; ++q) {
                float4 a = g[q * 4 + 0], b2 = g[q * 4 + 1];
                float4 c2 = g[q * 4 + 2], e2 = g[q * 4 + 3];
                GRP16_ASM(a, b2, c2, e2)
            }
        }
        {   // tail 15 steps: dsrev[2032..2046]; parity mask 0x2AAA (C macros)
            float4 a = d4[508], b2 = d4[509], c2 = d4[510], e2 = d4[511];
            STEP_B(a.x)  STEP_A(a.y)  STEP_B(a.z)  STEP_A(a.w)
            STEP_B(b2.x) STEP_A(b2.y) STEP_B(b2.z) STEP_A(b2.w)
            STEP_B(c2.x) STEP_A(c2.y) STEP_B(c2.z) STEP_A(c2.w)
            STEP_B(e2.x) STEP_A(e2.y) STEP_B(e2.z)
            unsigned xx = ((r ^ (r >> 1)) ^ 0x2AAAu) & 0x7FFFu;
            cnt += (unsigned)__builtin_popcount(xx);
        }
        shB1[xi] = pm1; shB2[xi] = pm2; shCB[xi] = (int)cnt;
    }
    __syncthreads();
    if (dir == 0) {
        // twist combine at m=2048: gammaN = -(Dm-X)u'1w'1 - u'2w'1 + u'1w'2;
        // [gamma<0] = !(sg^su^sw)
        float u1 = pm1, u2 = pm2;
        float w1 = shB1[xi], w2 = shB2[xi];
        float Dm = ds[2048];
        float gg = -(Dm - X) * u1 * w1 - u2 * w1 + u1 * w2;
        unsigned sx = (__float_as_uint(gg) ^ __float_as_uint(u1) ^
                       __float_as_uint(w1)) >> 31;
        counts[(l << 15) + j] = (int)(cnt + (unsigned)shCB[xi] + (sx ^ 1u));
    }
}

// ------------- final: bracket search (noise-tolerant) + midpoint -------------
__global__ __launch_bounds__(256) void final_eig(const int* __restrict__ counts,
                                                 const unsigned* __restrict__ bu,
                                                 float* __restrict__ out) {
    int e = blockIdx.x * 256 + threadIdx.x;       // 8192 eigenvalues (l,k)
    int l = e >> 12, k = e & (RN - 1);
    const int* c = counts + (l << 15);
    int lo_i = 0, hi_i = G1 - 1;                  // last j with c[j] <= k
    while (lo_i < hi_i) {
        int mid = (lo_i + hi_i + 1) >> 1;
        if (c[mid] <= k) lo_i = mid; else hi_i = mid - 1;
    }
    while (lo_i > 0 && c[lo_i] > k) --lo_i;       // +-1 noise fixups
    while (lo_i < G1 - 1 && c[lo_i + 1] <= k) ++lo_i;
    float lo, cell;
    spect_bounds(bu, lo, cell);
    out[e] = lo + cell * ((float)lo_i + 0.5f);
}

extern "C" void kernel_launch(void* const* d_in, const int* in_sizes, int n_in,
                              void* d_out, int out_size, void* d_ws, size_t ws_size,
                              hipStream_t stream) {
    const float* energy = (const float*)d_in[0];
    const float* W1 = (const float*)d_in[1];
    const float* b1 = (const float*)d_in[2];
    const float* W2 = (const float*)d_in[3];
    const float* b2 = (const float*)d_in[4];
    const float* W3 = (const float*)d_in[5];
    const float* b3 = (const float*)d_in[6];
    float* out = (float*)d_out;                   // [RN] ptl, then [2*RN] eigenvalues

    float* ws = (float*)d_ws;
    float*    partA  = ws;                        // 131072 f32 (layers 1,3)
    float*    partB  = partA + 131072;            // 131072 f32 (layer 2)
    float*    D      = partB + 131072;            // 2*RN f32 (D0 | D1)
    unsigned* bu     = (unsigned*)(D + 2 * RN);   // 2 u32
    int*      counts = (int*)(bu + 4);            // 2*G1 i32 (256 KB)

    // ---- MLP: 3 GEMVs, fins fused into next layer's prologue (R14 config) ----
    part1 <<<dim3(8, 64),  256, 0, stream>>>(W1, energy, partA, bu);
    part2f<<<dim3(4, 128), 256, 0, stream>>>(W2, partA, b1, partB);
    part3f<<<dim3(16, 32), 256, 0, stream>>>(W3, partB, b2, partA);
    fin3  <<<RN / 256,     256, 0, stream>>>(partA, b3, out, D, bu);

    // ---- Eigenvalues: twisted Sturm, inline-asm fmac ping-pong core ----
    stage1<<<dim3(G1 / 128, 2), 256, 0, stream>>>(D, bu, counts);
    final_eig<<<2 * RN / 256, 256, 0, stream>>>(counts, bu, out + RN);
}